// Round 1
// baseline (251.377 us; speedup 1.0000x reference)
//
#include <hip/hip_runtime.h>
#include <hip/hip_bf16.h>
#include <stdint.h>

#define Bn  2
#define Tn  2048
#define Dn  1024
#define Hn  16
#define DHn 64
#define Mn  (Bn*Tn)

typedef __attribute__((ext_vector_type(8))) short short8;
typedef __attribute__((ext_vector_type(4))) float f32x4;

__device__ __forceinline__ f32x4 fzero4() { f32x4 z = {0.f, 0.f, 0.f, 0.f}; return z; }

// ---------------- f32 -> bf16 ----------------
__global__ void cvt_bf16_kernel(const float* __restrict__ in,
                                __hip_bfloat16* __restrict__ out, int n)
{
    int i = (blockIdx.x * blockDim.x + threadIdx.x) * 4;
    if (i >= n) return;
    float4 v = *(const float4*)(in + i);
    union { __hip_bfloat16 h[4]; ushort4 u; } tmp;
    tmp.h[0] = __float2bfloat16(v.x);
    tmp.h[1] = __float2bfloat16(v.y);
    tmp.h[2] = __float2bfloat16(v.z);
    tmp.h[3] = __float2bfloat16(v.w);
    *(ushort4*)(out + i) = tmp.u;
}

// ---------------- GEMM: C[M,N] = A[M,K] * Bw[N,K]^T + bias ----------------
// 128x128 tile, BK=32, 4 waves (2x2), 16x16x32 bf16 MFMA, swizzled LDS.
template<int OUT_F32>
__global__ __launch_bounds__(256, 2)
void gemm_bt_kernel(const __hip_bfloat16* __restrict__ A,
                    const __hip_bfloat16* __restrict__ Bw,
                    const float* __restrict__ bias,
                    void* __restrict__ C, int M, int N, int K)
{
    __shared__ alignas(16) short As[128*32];
    __shared__ alignas(16) short Bs[128*32];
    const int t = threadIdx.x, lane = t & 63, wave = t >> 6;
    const int wm = wave >> 1, wn = wave & 1;
    const int row0 = blockIdx.x * 128, col0 = blockIdx.y * 128;

    f32x4 acc[4][4];
#pragma unroll
    for (int m = 0; m < 4; ++m)
#pragma unroll
        for (int n = 0; n < 4; ++n) acc[m][n] = fzero4();

    const int s_r0 = lane >> 2;          // row within 16-row chunk
    const int s_ke = (lane & 3) * 8;     // k element offset

    for (int k0 = 0; k0 < K; k0 += 32) {
        short8 ra[2], rb[2];
#pragma unroll
        for (int it = 0; it < 2; ++it) {
            const int r = (it*4 + wave)*16 + s_r0;
            ra[it] = *(const short8*)(A  + (size_t)(row0 + r)*K + k0 + s_ke);
            rb[it] = *(const short8*)(Bw + (size_t)(col0 + r)*K + k0 + s_ke);
        }
        __syncthreads();   // prior iteration's frag reads complete
#pragma unroll
        for (int it = 0; it < 2; ++it) {
            const int r = (it*4 + wave)*16 + s_r0;
            const int cb = (s_ke*2) ^ (((r>>1)&3)<<4);   // swizzle within 64B row
            *(short8*)((char*)As + r*64 + cb) = ra[it];
            *(short8*)((char*)Bs + r*64 + cb) = rb[it];
        }
        __syncthreads();
        short8 af[4], bfr[4];
#pragma unroll
        for (int m = 0; m < 4; ++m) {
            const int r = wm*64 + m*16 + (lane & 15);
            af[m] = *(const short8*)((char*)As + r*64 + (((lane>>4)*16) ^ (((r>>1)&3)<<4)));
        }
#pragma unroll
        for (int n = 0; n < 4; ++n) {
            const int r = wn*64 + n*16 + (lane & 15);
            bfr[n] = *(const short8*)((char*)Bs + r*64 + (((lane>>4)*16) ^ (((r>>1)&3)<<4)));
        }
#pragma unroll
        for (int m = 0; m < 4; ++m)
#pragma unroll
            for (int n = 0; n < 4; ++n)
                acc[m][n] = __builtin_amdgcn_mfma_f32_16x16x32_bf16(af[m], bfr[n], acc[m][n], 0, 0, 0);
    }

#pragma unroll
    for (int n = 0; n < 4; ++n) {
        const int col = col0 + wn*64 + n*16 + (lane & 15);
        const float bv = bias[col];
#pragma unroll
        for (int m = 0; m < 4; ++m) {
            const int rb_ = row0 + wm*64 + m*16 + (lane>>4)*4;
#pragma unroll
            for (int i = 0; i < 4; ++i) {
                const float vv = acc[m][n][i] + bv;
                if (OUT_F32) ((float*)C)[(size_t)(rb_+i)*N + col] = vv;
                else ((__hip_bfloat16*)C)[(size_t)(rb_+i)*N + col] = __float2bfloat16(vv);
            }
        }
    }
}

// ---------------- flash attention fwd ----------------
// grid = B*H*(T/64); 4 waves x 16 q-rows; KV tile 64; online softmax.
__global__ __launch_bounds__(256, 2)
void attn_kernel(const __hip_bfloat16* __restrict__ Q,
                 const __hip_bfloat16* __restrict__ K,
                 const __hip_bfloat16* __restrict__ V,
                 __hip_bfloat16* __restrict__ O)
{
    __shared__ alignas(16) short Ks[64*64];      // [kv][dh], swizzled
    __shared__ alignas(16) short Vt[64*64];      // [dh][kv], swizzled
    __shared__ alignas(16) short Ps[4][16*64];   // per-wave P, [qrow][kv], swizzled

    const int t = threadIdx.x, lane = t & 63, wave = t >> 6;
    const int blk = blockIdx.x;
    const int qb = blk & 31;
    const int h  = (blk >> 5) & (Hn - 1);
    const int b  = blk >> 9;
    const size_t base = (size_t)b * Tn * Dn + (size_t)h * DHn;
    const int q0 = qb * 64 + wave * 16;

    // Q fragments (A-operand): row = lane&15, k = (lane>>4)*8 + j (+32*ks)
    short8 aq[2];
    {
        const __hip_bfloat16* qp = Q + base + (size_t)(q0 + (lane & 15)) * Dn + (lane >> 4) * 8;
        aq[0] = *(const short8*)qp;
        aq[1] = *(const short8*)(qp + 32);
    }

    f32x4 o[4];
#pragma unroll
    for (int i = 0; i < 4; ++i) o[i] = fzero4();
    float mrow[4] = {-1e30f, -1e30f, -1e30f, -1e30f};
    float lrow[4] = {0.f, 0.f, 0.f, 0.f};
    const float cexp = 0.18033688011112042f;   // (1/sqrt(64)) * log2(e)

    const int ks_r  = t >> 3;          // K stage: row (0..31), +32 for chunk 1
    const int ks_cb = (t & 7) * 16;    // K stage: byte col in 128B row
    const int vt_r  = t >> 2;          // V stage: kv row 0..63
    const int vt_c  = (t & 3) * 16;    // V stage: dh col base

    for (int kv0 = 0; kv0 < Tn; kv0 += 64) {
        short8 kreg[2], vreg[2];
#pragma unroll
        for (int c = 0; c < 2; ++c)
            kreg[c] = *(const short8*)(K + base + (size_t)(kv0 + c*32 + ks_r)*Dn + ks_cb/2);
        vreg[0] = *(const short8*)(V + base + (size_t)(kv0 + vt_r)*Dn + vt_c);
        vreg[1] = *(const short8*)(V + base + (size_t)(kv0 + vt_r)*Dn + vt_c + 8);
        __syncthreads();   // prior iteration's LDS reads complete
#pragma unroll
        for (int c = 0; c < 2; ++c) {
            const int r = c*32 + ks_r;
            *(short8*)((char*)Ks + r*128 + (ks_cb ^ ((r&7)<<4))) = kreg[c];
        }
#pragma unroll
        for (int half = 0; half < 2; ++half)
#pragma unroll
            for (int j = 0; j < 8; ++j) {
                const int c0 = vt_c + half*8 + j;     // dh index = Vt row
                *(short*)((char*)Vt + c0*128 + ((vt_r*2) ^ ((c0&7)<<4))) = vreg[half][j];
            }
        __syncthreads();

        // S = Q K^T  (raw logits; scale folded into cexp)
        f32x4 s[4];
#pragma unroll
        for (int tt = 0; tt < 4; ++tt) s[tt] = fzero4();
#pragma unroll
        for (int ks = 0; ks < 2; ++ks)
#pragma unroll
            for (int tt = 0; tt < 4; ++tt) {
                const int r = tt*16 + (lane & 15);
                short8 bk = *(const short8*)((char*)Ks + r*128 + ((ks*64 + (lane>>4)*16) ^ ((r&7)<<4)));
                s[tt] = __builtin_amdgcn_mfma_f32_16x16x32_bf16(aq[ks], bk, s[tt], 0, 0, 0);
            }

        // online softmax, per accumulator row i (q-row = (lane>>4)*4 + i)
#pragma unroll
        for (int i = 0; i < 4; ++i) {
            float rm = fmaxf(fmaxf(s[0][i], s[1][i]), fmaxf(s[2][i], s[3][i]));
            rm = fmaxf(rm, __shfl_xor(rm, 1));
            rm = fmaxf(rm, __shfl_xor(rm, 2));
            rm = fmaxf(rm, __shfl_xor(rm, 4));
            rm = fmaxf(rm, __shfl_xor(rm, 8));
            const float mn = fmaxf(mrow[i], rm);
            const float sc = exp2f((mrow[i] - mn) * cexp);
            mrow[i] = mn;
            const int prow = (lane>>4)*4 + i;
            float rs = 0.f;
#pragma unroll
            for (int tt = 0; tt < 4; ++tt) {
                const float p = exp2f((s[tt][i] - mn) * cexp);
                rs += p;
                const int colb = ((lane & 15) + 16*tt) * 2;
                *(__hip_bfloat16*)((char*)Ps[wave] + prow*128 + (colb ^ ((prow&7)<<4)))
                    = __float2bfloat16(p);
            }
            rs += __shfl_xor(rs, 1);
            rs += __shfl_xor(rs, 2);
            rs += __shfl_xor(rs, 4);
            rs += __shfl_xor(rs, 8);
            lrow[i] = lrow[i] * sc + rs;
#pragma unroll
            for (int t2 = 0; t2 < 4; ++t2) o[t2][i] *= sc;
        }

        // O += P~ V
#pragma unroll
        for (int ks = 0; ks < 2; ++ks) {
            const int pr = lane & 15;
            short8 ap = *(const short8*)((char*)Ps[wave] + pr*128 + ((ks*64 + (lane>>4)*16) ^ ((pr&7)<<4)));
#pragma unroll
            for (int t2 = 0; t2 < 4; ++t2) {
                const int vr = t2*16 + (lane & 15);
                short8 bv = *(const short8*)((char*)Vt + vr*128 + ((ks*64 + (lane>>4)*16) ^ ((vr&7)<<4)));
                o[t2] = __builtin_amdgcn_mfma_f32_16x16x32_bf16(ap, bv, o[t2], 0, 0, 0);
            }
        }
    }

#pragma unroll
    for (int i = 0; i < 4; ++i) {
        const float inv = 1.f / lrow[i];
        const size_t rowoff = base + (size_t)(q0 + (lane>>4)*4 + i) * Dn;
#pragma unroll
        for (int t2 = 0; t2 < 4; ++t2)
            O[rowoff + t2*16 + (lane & 15)] = __float2bfloat16(o[t2][i] * inv);
    }
}

extern "C" void kernel_launch(void* const* d_in, const int* in_sizes, int n_in,
                              void* d_out, int out_size, void* d_ws, size_t ws_size,
                              hipStream_t stream)
{
    (void)in_sizes; (void)n_in; (void)out_size; (void)ws_size;
    const float* q    = (const float*)d_in[0];
    const float* k    = (const float*)d_in[1];
    const float* v    = (const float*)d_in[2];
    const float* wq_w = (const float*)d_in[3];
    const float* wq_b = (const float*)d_in[4];
    const float* wk_w = (const float*)d_in[5];
    const float* wk_b = (const float*)d_in[6];
    const float* wv_w = (const float*)d_in[7];
    const float* wv_b = (const float*)d_in[8];
    const float* wo_w = (const float*)d_in[9];
    const float* wo_b = (const float*)d_in[10];

    char* ws = (char*)d_ws;
    const size_t S1 = (size_t)Mn * Dn * 2;   // 8 MiB: one [4096,1024] bf16
    const size_t W  = (size_t)Dn * Dn * 2;   // 2 MiB: one [1024,1024] bf16
    __hip_bfloat16* qb  = (__hip_bfloat16*)(ws);
    __hip_bfloat16* kb  = (__hip_bfloat16*)(ws + S1);
    __hip_bfloat16* vb  = (__hip_bfloat16*)(ws + 2*S1);
    __hip_bfloat16* wqb = (__hip_bfloat16*)(ws + 3*S1);
    __hip_bfloat16* wkb = (__hip_bfloat16*)(ws + 3*S1 + W);
    __hip_bfloat16* wvb = (__hip_bfloat16*)(ws + 3*S1 + 2*W);
    __hip_bfloat16* wob = (__hip_bfloat16*)(ws + 3*S1 + 3*W);
    __hip_bfloat16* Qp  = (__hip_bfloat16*)(ws + 3*S1 + 4*W);
    __hip_bfloat16* Kp  = (__hip_bfloat16*)(ws + 4*S1 + 4*W);
    __hip_bfloat16* Vp  = (__hip_bfloat16*)(ws + 5*S1 + 4*W);
    __hip_bfloat16* Ap  = (__hip_bfloat16*)(ws + 6*S1 + 4*W);
    // total ws use: 7*S1 + 4*W = 64 MiB

    const int nQKV = Mn * Dn;   // 4194304
    const int nW   = Dn * Dn;   // 1048576
    cvt_bf16_kernel<<<nQKV/1024, 256, 0, stream>>>(q, qb, nQKV);
    cvt_bf16_kernel<<<nQKV/1024, 256, 0, stream>>>(k, kb, nQKV);
    cvt_bf16_kernel<<<nQKV/1024, 256, 0, stream>>>(v, vb, nQKV);
    cvt_bf16_kernel<<<nW/1024,   256, 0, stream>>>(wq_w, wqb, nW);
    cvt_bf16_kernel<<<nW/1024,   256, 0, stream>>>(wk_w, wkb, nW);
    cvt_bf16_kernel<<<nW/1024,   256, 0, stream>>>(wv_w, wvb, nW);
    cvt_bf16_kernel<<<nW/1024,   256, 0, stream>>>(wo_w, wob, nW);

    dim3 g(Mn/128, Dn/128);
    gemm_bt_kernel<0><<<g, 256, 0, stream>>>(qb, wqb, wq_b, Qp, Mn, Dn, Dn);
    gemm_bt_kernel<0><<<g, 256, 0, stream>>>(kb, wkb, wk_b, Kp, Mn, Dn, Dn);
    gemm_bt_kernel<0><<<g, 256, 0, stream>>>(vb, wvb, wv_b, Vp, Mn, Dn, Dn);

    attn_kernel<<<Bn*Hn*(Tn/64), 256, 0, stream>>>(Qp, Kp, Vp, Ap);

    gemm_bt_kernel<1><<<g, 256, 0, stream>>>(Ap, wob, wo_b, (float*)d_out, Mn, Dn, Dn);
}

// Round 2
// 212.081 us; speedup vs baseline: 1.1853x; 1.1853x over previous
//
#include <hip/hip_runtime.h>
#include <hip/hip_bf16.h>
#include <stdint.h>

#define Bn  2
#define Tn  2048
#define Dn  1024
#define Hn  16
#define DHn 64
#define Mn  (Bn*Tn)

typedef __attribute__((ext_vector_type(8))) short short8;
typedef __attribute__((ext_vector_type(4))) short short4v;
typedef __attribute__((ext_vector_type(4))) float f32x4;

__device__ __forceinline__ f32x4 fzero4() { f32x4 z = {0.f, 0.f, 0.f, 0.f}; return z; }

// hardware transpose read: lane l of 16-lane group g supplies addr = tile_base(g) + (l&15)*8B;
// result elem j = column (l&15), row j of the group's 4x16 bf16 tile (m156/m162 layout).
#define TR16(dst, a32) asm volatile("ds_read_b64_tr_b16 %0, %1" : "=v"(dst) : "v"(a32))

// ---------------- f32 -> bf16 ----------------
__global__ void cvt_bf16_kernel(const float* __restrict__ in,
                                __hip_bfloat16* __restrict__ out, int n)
{
    int i = (blockIdx.x * blockDim.x + threadIdx.x) * 4;
    if (i >= n) return;
    float4 v = *(const float4*)(in + i);
    union { __hip_bfloat16 h[4]; ushort4 u; } tmp;
    tmp.h[0] = __float2bfloat16(v.x);
    tmp.h[1] = __float2bfloat16(v.y);
    tmp.h[2] = __float2bfloat16(v.z);
    tmp.h[3] = __float2bfloat16(v.w);
    *(ushort4*)(out + i) = tmp.u;
}

// ---------------- GEMM: C[M,N] = A[M,K] * Bw[N,K]^T + bias ----------------
template<int OUT_F32>
__global__ __launch_bounds__(256, 2)
void gemm_bt_kernel(const __hip_bfloat16* __restrict__ A,
                    const __hip_bfloat16* __restrict__ Bw,
                    const float* __restrict__ bias,
                    void* __restrict__ C, int M, int N, int K)
{
    __shared__ alignas(16) short As[128*32];
    __shared__ alignas(16) short Bs[128*32];
    const int t = threadIdx.x, lane = t & 63, wave = t >> 6;
    const int wm = wave >> 1, wn = wave & 1;
    const int row0 = blockIdx.x * 128, col0 = blockIdx.y * 128;

    f32x4 acc[4][4];
#pragma unroll
    for (int m = 0; m < 4; ++m)
#pragma unroll
        for (int n = 0; n < 4; ++n) acc[m][n] = fzero4();

    const int s_r0 = lane >> 2;
    const int s_ke = (lane & 3) * 8;

    for (int k0 = 0; k0 < K; k0 += 32) {
        short8 ra[2], rb[2];
#pragma unroll
        for (int it = 0; it < 2; ++it) {
            const int r = (it*4 + wave)*16 + s_r0;
            ra[it] = *(const short8*)(A  + (size_t)(row0 + r)*K + k0 + s_ke);
            rb[it] = *(const short8*)(Bw + (size_t)(col0 + r)*K + k0 + s_ke);
        }
        __syncthreads();
#pragma unroll
        for (int it = 0; it < 2; ++it) {
            const int r = (it*4 + wave)*16 + s_r0;
            const int cb = (s_ke*2) ^ (((r>>1)&3)<<4);
            *(short8*)((char*)As + r*64 + cb) = ra[it];
            *(short8*)((char*)Bs + r*64 + cb) = rb[it];
        }
        __syncthreads();
        short8 af[4], bfr[4];
#pragma unroll
        for (int m = 0; m < 4; ++m) {
            const int r = wm*64 + m*16 + (lane & 15);
            af[m] = *(const short8*)((char*)As + r*64 + (((lane>>4)*16) ^ (((r>>1)&3)<<4)));
        }
#pragma unroll
        for (int n = 0; n < 4; ++n) {
            const int r = wn*64 + n*16 + (lane & 15);
            bfr[n] = *(const short8*)((char*)Bs + r*64 + (((lane>>4)*16) ^ (((r>>1)&3)<<4)));
        }
#pragma unroll
        for (int m = 0; m < 4; ++m)
#pragma unroll
            for (int n = 0; n < 4; ++n)
                acc[m][n] = __builtin_amdgcn_mfma_f32_16x16x32_bf16(af[m], bfr[n], acc[m][n], 0, 0, 0);
    }

#pragma unroll
    for (int n = 0; n < 4; ++n) {
        const int col = col0 + wn*64 + n*16 + (lane & 15);
        const float bv = bias[col];
#pragma unroll
        for (int m = 0; m < 4; ++m) {
            const int rb_ = row0 + wm*64 + m*16 + (lane>>4)*4;
#pragma unroll
            for (int i = 0; i < 4; ++i) {
                const float vv = acc[m][n][i] + bv;
                if (OUT_F32) ((float*)C)[(size_t)(rb_+i)*N + col] = vv;
                else ((__hip_bfloat16*)C)[(size_t)(rb_+i)*N + col] = __float2bfloat16(vv);
            }
        }
    }
}

// ---------------- flash attention fwd (swapped-operand, in-register softmax) ----
// grid = B*H*(T/128); 4 waves x 32 q-rows; KV tile 64.
// S^T = mfma(K, Q): lane owns q = qs*16 + (lane&15); kv = sub*16 + (lane>>4)*4 + i.
// PV swapped: O^T = mfma(V^T, P^T) with shared k-permutation
//   perm(g*8+j) = (j>>2)*16 + g*4 + (j&3) (relative to kc*32).
// V in LDS subtiled planes: elem(kv,dh) = (dh>>4)*1288 + (kv>>2)*80 + (kv&3)*16 + (dh&15).
#define VPL 1288   // plane stride (elems); kb stride 80 (16 tiles of 64 + 16 pad)

__global__ __launch_bounds__(256, 2)
void attn_kernel(const __hip_bfloat16* __restrict__ Q,
                 const __hip_bfloat16* __restrict__ K,
                 const __hip_bfloat16* __restrict__ V,
                 __hip_bfloat16* __restrict__ O)
{
    __shared__ alignas(16) short Vlds[4*VPL];
    const int t = threadIdx.x, lane = t & 63, wave = t >> 6;
    const int g = lane >> 4, c = lane & 15;
    const int blk = blockIdx.x;
    const int qb = blk & 15;
    const int h  = (blk >> 4) & (Hn - 1);
    const int b  = blk >> 8;
    const size_t base = (size_t)b * Tn * Dn + (size_t)h * DHn;
    const int q0 = qb * 128 + wave * 32;

    // Q fragments (B-operand of swapped QK^T): col = q, k = dh
    short8 bq[2][2];
#pragma unroll
    for (int qs = 0; qs < 2; ++qs) {
        const __hip_bfloat16* qp = Q + base + (size_t)(q0 + qs*16 + c) * Dn + g*8;
        bq[qs][0] = *(const short8*)qp;
        bq[qs][1] = *(const short8*)(qp + 32);
    }

    f32x4 o_[2][4];
#pragma unroll
    for (int qs = 0; qs < 2; ++qs)
#pragma unroll
        for (int d = 0; d < 4; ++d) o_[qs][d] = fzero4();
    float m_[2] = {-3e38f, -3e38f};
    float l_[2] = {0.f, 0.f};
    const float cexp = 0.18033688011112042f;   // log2(e)/sqrt(64)

    // V staging: 512 units of 8 elems; thread does units t and t+256.
    const int vrow = t >> 3;            // kv row 0..31 (unit0), +32 (unit1)
    const int vc   = (t >> 1) & 3;      // dh plane
    const int vh   = t & 1;             // 8-elem half
    const int vdst0 = vc*VPL + (vrow>>2)*80 + (vrow&3)*16 + vh*8;

    // tr-read lane address: tile_base(plane,kb) + (lane&15)*8 bytes; group g -> kb=kc*8+g
    const uint32_t vbase = (uint32_t)(uintptr_t)(void*)Vlds;   // LDS byte offset
    const uint32_t atr = vbase + (uint32_t)(g*160 + c*8);

    for (int kv0 = 0; kv0 < Tn; kv0 += 64) {
        // V global loads (issued early; consumed after barrier)
        const __hip_bfloat16* vp = V + base + (size_t)(kv0 + vrow) * Dn + vc*16 + vh*8;
        short8 vr0 = *(const short8*)vp;
        short8 vr1 = *(const short8*)(vp + (size_t)32*Dn);

        // K fragments (A-operand): row = kv, k = dh
        short8 ak[4][2];
        const __hip_bfloat16* kp = K + base + (size_t)(kv0 + c) * Dn + g*8;
#pragma unroll
        for (int sub = 0; sub < 4; ++sub)
#pragma unroll
            for (int ks = 0; ks < 2; ++ks)
                ak[sub][ks] = *(const short8*)(kp + (size_t)sub*16*Dn + ks*32);

        // S^T[kv][q]
        f32x4 s_[2][4];
#pragma unroll
        for (int qs = 0; qs < 2; ++qs)
#pragma unroll
            for (int sub = 0; sub < 4; ++sub) s_[qs][sub] = fzero4();
#pragma unroll
        for (int qs = 0; qs < 2; ++qs)
#pragma unroll
            for (int sub = 0; sub < 4; ++sub)
#pragma unroll
                for (int ks = 0; ks < 2; ++ks)
                    s_[qs][sub] = __builtin_amdgcn_mfma_f32_16x16x32_bf16(
                        ak[sub][ks], bq[qs][ks], s_[qs][sub], 0, 0, 0);

        // online softmax, fully in-register; P packed as PV B-operand fragments
        short8 pa[2][2];
#pragma unroll
        for (int qs = 0; qs < 2; ++qs) {
            float rm = s_[qs][0][0];
#pragma unroll
            for (int sub = 0; sub < 4; ++sub)
#pragma unroll
                for (int i = 0; i < 4; ++i) rm = fmaxf(rm, s_[qs][sub][i]);
            rm = fmaxf(rm, __shfl_xor(rm, 16));
            rm = fmaxf(rm, __shfl_xor(rm, 32));
            const float mn = fmaxf(m_[qs], rm);
            const float sc = exp2f((m_[qs] - mn) * cexp);
            m_[qs] = mn;
            float rs = 0.f;
#pragma unroll
            for (int kc = 0; kc < 2; ++kc)
#pragma unroll
                for (int hf = 0; hf < 2; ++hf) {
                    const int sub = kc*2 + hf;
#pragma unroll
                    for (int i = 0; i < 4; ++i) {
                        const float p = exp2f((s_[qs][sub][i] - mn) * cexp);
                        rs += p;
                        union { __hip_bfloat16 hb; short u; } cv;
                        cv.hb = __float2bfloat16(p);
                        pa[qs][kc][hf*4 + i] = cv.u;
                    }
                }
            rs += __shfl_xor(rs, 16);
            rs += __shfl_xor(rs, 32);
            l_[qs] = l_[qs] * sc + rs;
#pragma unroll
            for (int d = 0; d < 4; ++d)
#pragma unroll
                for (int i = 0; i < 4; ++i) o_[qs][d][i] *= sc;
        }

        __syncthreads();                 // prev tile tr-reads done (lgkmcnt drained)
        *(short8*)(&Vlds[vdst0])       = vr0;
        *(short8*)(&Vlds[vdst0 + 640]) = vr1;   // row+32 -> kb+8
        __syncthreads();

        // PV: O^T += V^T * P^T
        short4v tv[4][2][2];
#pragma unroll
        for (int d = 0; d < 4; ++d)
#pragma unroll
            for (int kc = 0; kc < 2; ++kc) {
                const uint32_t a = atr + (uint32_t)(d*2576 + kc*1280);
                TR16(tv[d][kc][0], a);
                TR16(tv[d][kc][1], a + 640);
            }
        asm volatile("s_waitcnt lgkmcnt(0)" ::: "memory");
        __builtin_amdgcn_sched_barrier(0);
#pragma unroll
        for (int d = 0; d < 4; ++d) {
            const short8 av0 = __builtin_shufflevector(tv[d][0][0], tv[d][0][1], 0,1,2,3,4,5,6,7);
            const short8 av1 = __builtin_shufflevector(tv[d][1][0], tv[d][1][1], 0,1,2,3,4,5,6,7);
#pragma unroll
            for (int qs = 0; qs < 2; ++qs) {
                o_[qs][d] = __builtin_amdgcn_mfma_f32_16x16x32_bf16(av0, pa[qs][0], o_[qs][d], 0, 0, 0);
                o_[qs][d] = __builtin_amdgcn_mfma_f32_16x16x32_bf16(av1, pa[qs][1], o_[qs][d], 0, 0, 0);
            }
        }
    }

    // epilogue: O[q][dh], q = q0+qs*16+c, dh = d*16 + g*4 + i
#pragma unroll
    for (int qs = 0; qs < 2; ++qs) {
        const float inv = 1.f / l_[qs];
        __hip_bfloat16* op = O + base + (size_t)(q0 + qs*16 + c) * Dn + g*4;
#pragma unroll
        for (int d = 0; d < 4; ++d) {
            union { __hip_bfloat16 hb[4]; ushort4 u4; } w;
#pragma unroll
            for (int i = 0; i < 4; ++i) w.hb[i] = __float2bfloat16(o_[qs][d][i] * inv);
            *(ushort4*)(op + d*16) = w.u4;
        }
    }
}

extern "C" void kernel_launch(void* const* d_in, const int* in_sizes, int n_in,
                              void* d_out, int out_size, void* d_ws, size_t ws_size,
                              hipStream_t stream)
{
    (void)in_sizes; (void)n_in; (void)out_size; (void)ws_size;
    const float* q    = (const float*)d_in[0];
    const float* k    = (const float*)d_in[1];
    const float* v    = (const float*)d_in[2];
    const float* wq_w = (const float*)d_in[3];
    const float* wq_b = (const float*)d_in[4];
    const float* wk_w = (const float*)d_in[5];
    const float* wk_b = (const float*)d_in[6];
    const float* wv_w = (const float*)d_in[7];
    const float* wv_b = (const float*)d_in[8];
    const float* wo_w = (const float*)d_in[9];
    const float* wo_b = (const float*)d_in[10];

    char* ws = (char*)d_ws;
    const size_t S1 = (size_t)Mn * Dn * 2;
    const size_t W  = (size_t)Dn * Dn * 2;
    __hip_bfloat16* qb  = (__hip_bfloat16*)(ws);
    __hip_bfloat16* kb  = (__hip_bfloat16*)(ws + S1);
    __hip_bfloat16* vb  = (__hip_bfloat16*)(ws + 2*S1);
    __hip_bfloat16* wqb = (__hip_bfloat16*)(ws + 3*S1);
    __hip_bfloat16* wkb = (__hip_bfloat16*)(ws + 3*S1 + W);
    __hip_bfloat16* wvb = (__hip_bfloat16*)(ws + 3*S1 + 2*W);
    __hip_bfloat16* wob = (__hip_bfloat16*)(ws + 3*S1 + 3*W);
    __hip_bfloat16* Qp  = (__hip_bfloat16*)(ws + 3*S1 + 4*W);
    __hip_bfloat16* Kp  = (__hip_bfloat16*)(ws + 4*S1 + 4*W);
    __hip_bfloat16* Vp  = (__hip_bfloat16*)(ws + 5*S1 + 4*W);
    __hip_bfloat16* Ap  = (__hip_bfloat16*)(ws + 6*S1 + 4*W);

    const int nQKV = Mn * Dn;
    const int nW   = Dn * Dn;
    cvt_bf16_kernel<<<nQKV/1024, 256, 0, stream>>>(q, qb, nQKV);
    cvt_bf16_kernel<<<nQKV/1024, 256, 0, stream>>>(k, kb, nQKV);
    cvt_bf16_kernel<<<nQKV/1024, 256, 0, stream>>>(v, vb, nQKV);
    cvt_bf16_kernel<<<nW/1024,   256, 0, stream>>>(wq_w, wqb, nW);
    cvt_bf16_kernel<<<nW/1024,   256, 0, stream>>>(wk_w, wkb, nW);
    cvt_bf16_kernel<<<nW/1024,   256, 0, stream>>>(wv_w, wvb, nW);
    cvt_bf16_kernel<<<nW/1024,   256, 0, stream>>>(wo_w, wob, nW);

    dim3 g(Mn/128, Dn/128);
    gemm_bt_kernel<0><<<g, 256, 0, stream>>>(qb, wqb, wq_b, Qp, Mn, Dn, Dn);
    gemm_bt_kernel<0><<<g, 256, 0, stream>>>(kb, wkb, wk_b, Kp, Mn, Dn, Dn);
    gemm_bt_kernel<0><<<g, 256, 0, stream>>>(vb, wvb, wv_b, Vp, Mn, Dn, Dn);

    attn_kernel<<<Bn*Hn*(Tn/128), 256, 0, stream>>>(Qp, Kp, Vp, Ap);

    gemm_bt_kernel<1><<<g, 256, 0, stream>>>(Ap, wob, wo_b, (float*)d_out, Mn, Dn, Dn);
}

// Round 3
// 196.525 us; speedup vs baseline: 1.2791x; 1.0792x over previous
//
#include <hip/hip_runtime.h>
#include <hip/hip_bf16.h>
#include <stdint.h>

#define Bn  2
#define Tn  2048
#define Dn  1024
#define Hn  16
#define DHn 64
#define Mn  (Bn*Tn)

typedef __attribute__((ext_vector_type(8))) short short8;
typedef __attribute__((ext_vector_type(4))) short short4v;
typedef __attribute__((ext_vector_type(4))) float f32x4;

__device__ __forceinline__ f32x4 fzero4() { f32x4 z = {0.f, 0.f, 0.f, 0.f}; return z; }

#define TR16(dst, a32) asm volatile("ds_read_b64_tr_b16 %0, %1" : "=v"(dst) : "v"(a32))

// ---------------- f32 -> bf16, batched (blockIdx.y selects tensor) ----------
__global__ void cvt3_kernel(const float* __restrict__ a0, const float* __restrict__ a1,
                            const float* __restrict__ a2,
                            __hip_bfloat16* __restrict__ o0, __hip_bfloat16* __restrict__ o1,
                            __hip_bfloat16* __restrict__ o2, int n)
{
    const int i = (blockIdx.x * blockDim.x + threadIdx.x) * 8;
    if (i >= n) return;
    const float* in = blockIdx.y == 0 ? a0 : (blockIdx.y == 1 ? a1 : a2);
    __hip_bfloat16* out = blockIdx.y == 0 ? o0 : (blockIdx.y == 1 ? o1 : o2);
    float4 a = *(const float4*)(in + i);
    float4 b = *(const float4*)(in + i + 4);
    union { __hip_bfloat16 h[8]; short8 u; } tmp;
    tmp.h[0] = __float2bfloat16(a.x); tmp.h[1] = __float2bfloat16(a.y);
    tmp.h[2] = __float2bfloat16(a.z); tmp.h[3] = __float2bfloat16(a.w);
    tmp.h[4] = __float2bfloat16(b.x); tmp.h[5] = __float2bfloat16(b.y);
    tmp.h[6] = __float2bfloat16(b.z); tmp.h[7] = __float2bfloat16(b.w);
    *(short8*)(out + i) = tmp.u;
}

__global__ void cvt4_kernel(const float* __restrict__ a0, const float* __restrict__ a1,
                            const float* __restrict__ a2, const float* __restrict__ a3,
                            __hip_bfloat16* __restrict__ o0, __hip_bfloat16* __restrict__ o1,
                            __hip_bfloat16* __restrict__ o2, __hip_bfloat16* __restrict__ o3, int n)
{
    const int i = (blockIdx.x * blockDim.x + threadIdx.x) * 8;
    if (i >= n) return;
    const float* in = blockIdx.y == 0 ? a0 : (blockIdx.y == 1 ? a1 : (blockIdx.y == 2 ? a2 : a3));
    __hip_bfloat16* out = blockIdx.y == 0 ? o0 : (blockIdx.y == 1 ? o1 : (blockIdx.y == 2 ? o2 : o3));
    float4 a = *(const float4*)(in + i);
    float4 b = *(const float4*)(in + i + 4);
    union { __hip_bfloat16 h[8]; short8 u; } tmp;
    tmp.h[0] = __float2bfloat16(a.x); tmp.h[1] = __float2bfloat16(a.y);
    tmp.h[2] = __float2bfloat16(a.z); tmp.h[3] = __float2bfloat16(a.w);
    tmp.h[4] = __float2bfloat16(b.x); tmp.h[5] = __float2bfloat16(b.y);
    tmp.h[6] = __float2bfloat16(b.z); tmp.h[7] = __float2bfloat16(b.w);
    *(short8*)(out + i) = tmp.u;
}

// ---------------- GEMM: C[M,N] = A[M,K] * Bw[N,K]^T + bias ----------------
// 128x128 tile, BK=32, 4 waves, global_load_lds(16B) staging, double-buffered
// LDS, one barrier per K-step (T3-minimal 2-phase).
template<int OUT_F32>
__global__ __launch_bounds__(256, 2)
void gemm_bt_kernel(const __hip_bfloat16* __restrict__ A,
                    const __hip_bfloat16* __restrict__ Bw,
                    const float* __restrict__ bias,
                    void* __restrict__ C, int M, int N, int K)
{
    __shared__ alignas(16) short As[2][128*32];
    __shared__ alignas(16) short Bs[2][128*32];
    const int t = threadIdx.x, lane = t & 63, wave = t >> 6;
    const int wm = wave >> 1, wn = wave & 1;
    const int row0 = blockIdx.x * 128, col0 = blockIdx.y * 128;

    f32x4 acc[4][4];
#pragma unroll
    for (int m = 0; m < 4; ++m)
#pragma unroll
        for (int n = 0; n < 4; ++n) acc[m][n] = fzero4();

    // staging map: load i, wave w, lane l -> LDS byte i*4096 + w*1024 + l*16
    //   row = i*64 + w*16 + l/4, k-elem = (l&3)*8   (linear [row][32] bf16, 64B rows)
    const int srow = wave*16 + (lane >> 2);
    const int skk  = (lane & 3) * 8;
    const int ldsb = wave * 1024;

    auto STAGE = [&](int buf, int k0) {
#pragma unroll
        for (int i = 0; i < 2; ++i) {
            __builtin_amdgcn_global_load_lds(
                (const __attribute__((address_space(1))) void*)(A + (size_t)(row0 + i*64 + srow)*K + k0 + skk),
                (__attribute__((address_space(3))) void*)((char*)As[buf] + i*4096 + ldsb), 16, 0, 0);
            __builtin_amdgcn_global_load_lds(
                (const __attribute__((address_space(1))) void*)(Bw + (size_t)(col0 + i*64 + srow)*K + k0 + skk),
                (__attribute__((address_space(3))) void*)((char*)Bs[buf] + i*4096 + ldsb), 16, 0, 0);
        }
    };

    STAGE(0, 0);
    __syncthreads();               // drains vmcnt(0): buf0 staged for all
    int cur = 0;
    for (int k0 = 0; k0 < K; k0 += 32) {
        if (k0 + 32 < K) STAGE(cur ^ 1, k0 + 32);   // issue next-tile loads early
        short8 af[4], bf_[4];
#pragma unroll
        for (int m = 0; m < 4; ++m)
            af[m] = *(const short8*)((char*)As[cur] + (wm*64 + m*16 + (lane & 15))*64 + (lane >> 4)*16);
#pragma unroll
        for (int n = 0; n < 4; ++n)
            bf_[n] = *(const short8*)((char*)Bs[cur] + (wn*64 + n*16 + (lane & 15))*64 + (lane >> 4)*16);
#pragma unroll
        for (int m = 0; m < 4; ++m)
#pragma unroll
            for (int n = 0; n < 4; ++n)
                acc[m][n] = __builtin_amdgcn_mfma_f32_16x16x32_bf16(af[m], bf_[n], acc[m][n], 0, 0, 0);
        __syncthreads();           // all reads of cur done AND next staged (vmcnt drain)
        cur ^= 1;
    }

#pragma unroll
    for (int n = 0; n < 4; ++n) {
        const int col = col0 + wn*64 + n*16 + (lane & 15);
        const float bv = bias[col];
#pragma unroll
        for (int m = 0; m < 4; ++m) {
            const int rb_ = row0 + wm*64 + m*16 + (lane>>4)*4;
#pragma unroll
            for (int i = 0; i < 4; ++i) {
                const float vv = acc[m][n][i] + bv;
                if (OUT_F32) ((float*)C)[(size_t)(rb_+i)*N + col] = vv;
                else ((__hip_bfloat16*)C)[(size_t)(rb_+i)*N + col] = __float2bfloat16(vv);
            }
        }
    }
}

// ---------------- flash attention fwd (pipelined, swapped-operand) ----------
#define VPL 1288

__device__ __forceinline__ void attn_tile(
    const short8 (&ck)[4][2], const short8 (&cv)[2],
    short8 (&nk)[4][2], short8 (&nv)[2], int kvn,
    const short8 (&bq)[2][2], f32x4 (&o_)[2][4], float (&m_)[2], float (&l_)[2],
    const __hip_bfloat16* K, const __hip_bfloat16* V, size_t base,
    int c, int g, int vrow, int vc, int vh, int vdst0, uint32_t atr, short* Vlds)
{
    const float cexp = 0.18033688011112042f;   // log2(e)/sqrt(64)

    // ---- prefetch next tile's K and V into registers (issue only) ----
    {
        const __hip_bfloat16* kp = K + base + (size_t)(kvn + c) * Dn + g*8;
#pragma unroll
        for (int sub = 0; sub < 4; ++sub)
#pragma unroll
            for (int ks = 0; ks < 2; ++ks)
                nk[sub][ks] = *(const short8*)(kp + (size_t)sub*16*Dn + ks*32);
        const __hip_bfloat16* vp = V + base + (size_t)(kvn + vrow) * Dn + vc*16 + vh*8;
        nv[0] = *(const short8*)vp;
        nv[1] = *(const short8*)(vp + (size_t)32*Dn);
    }

    // ---- S^T = K * Q (current tile, regs loaded one tile ago) ----
    f32x4 s_[2][4];
#pragma unroll
    for (int qs = 0; qs < 2; ++qs)
#pragma unroll
        for (int sub = 0; sub < 4; ++sub) s_[qs][sub] = fzero4();
    __builtin_amdgcn_s_setprio(1);
#pragma unroll
    for (int qs = 0; qs < 2; ++qs)
#pragma unroll
        for (int sub = 0; sub < 4; ++sub)
#pragma unroll
            for (int ks = 0; ks < 2; ++ks)
                s_[qs][sub] = __builtin_amdgcn_mfma_f32_16x16x32_bf16(
                    ck[sub][ks], bq[qs][ks], s_[qs][sub], 0, 0, 0);
    __builtin_amdgcn_s_setprio(0);

    // ---- online softmax with defer-max (T13), P packed in-register ----
    short8 pa[2][2];
#pragma unroll
    for (int qs = 0; qs < 2; ++qs) {
        float rm = s_[qs][0][0];
#pragma unroll
        for (int sub = 0; sub < 4; ++sub)
#pragma unroll
            for (int i = 0; i < 4; ++i) rm = fmaxf(rm, s_[qs][sub][i]);
        rm = fmaxf(rm, __shfl_xor(rm, 16));
        rm = fmaxf(rm, __shfl_xor(rm, 32));
        float rs = 0.f;
        if (__all((rm - m_[qs]) * cexp <= 8.0f)) {
            const float mn = m_[qs];                // keep old max; p <= 2^8
#pragma unroll
            for (int kc = 0; kc < 2; ++kc)
#pragma unroll
                for (int hf = 0; hf < 2; ++hf)
#pragma unroll
                    for (int i = 0; i < 4; ++i) {
                        const float p = exp2f((s_[qs][kc*2+hf][i] - mn) * cexp);
                        rs += p;
                        union { __hip_bfloat16 hb; short u; } cvp;
                        cvp.hb = __float2bfloat16(p);
                        pa[qs][kc][hf*4 + i] = cvp.u;
                    }
            rs += __shfl_xor(rs, 16);
            rs += __shfl_xor(rs, 32);
            l_[qs] += rs;
        } else {
            const float mn = fmaxf(m_[qs], rm);
            const float sc = exp2f((m_[qs] - mn) * cexp);
            m_[qs] = mn;
#pragma unroll
            for (int kc = 0; kc < 2; ++kc)
#pragma unroll
                for (int hf = 0; hf < 2; ++hf)
#pragma unroll
                    for (int i = 0; i < 4; ++i) {
                        const float p = exp2f((s_[qs][kc*2+hf][i] - mn) * cexp);
                        rs += p;
                        union { __hip_bfloat16 hb; short u; } cvp;
                        cvp.hb = __float2bfloat16(p);
                        pa[qs][kc][hf*4 + i] = cvp.u;
                    }
            rs += __shfl_xor(rs, 16);
            rs += __shfl_xor(rs, 32);
            l_[qs] = l_[qs] * sc + rs;
#pragma unroll
            for (int d = 0; d < 4; ++d)
#pragma unroll
                for (int i = 0; i < 4; ++i) o_[qs][d][i] *= sc;
        }
    }

    // ---- stage current V into LDS (raw barriers: no vmcnt drain) ----
    __builtin_amdgcn_s_barrier();             // everyone done tr-reading prev tile
    *(short8*)(&Vlds[vdst0])       = cv[0];
    *(short8*)(&Vlds[vdst0 + 640]) = cv[1];
    asm volatile("s_waitcnt lgkmcnt(0)" ::: "memory");
    __builtin_amdgcn_s_barrier();             // V tile visible to all
    __builtin_amdgcn_sched_barrier(0);

    // ---- PV: O^T += V^T * P^T (hardware transpose reads) ----
    short4v tv[4][2][2];
#pragma unroll
    for (int d = 0; d < 4; ++d)
#pragma unroll
        for (int kc = 0; kc < 2; ++kc) {
            const uint32_t a = atr + (uint32_t)(d*2576 + kc*1280);
            TR16(tv[d][kc][0], a);
            TR16(tv[d][kc][1], a + 640);
        }
    asm volatile("s_waitcnt lgkmcnt(0)" ::: "memory");
    __builtin_amdgcn_sched_barrier(0);
    __builtin_amdgcn_s_setprio(1);
#pragma unroll
    for (int d = 0; d < 4; ++d) {
        const short8 av0 = __builtin_shufflevector(tv[d][0][0], tv[d][0][1], 0,1,2,3,4,5,6,7);
        const short8 av1 = __builtin_shufflevector(tv[d][1][0], tv[d][1][1], 0,1,2,3,4,5,6,7);
#pragma unroll
        for (int qs = 0; qs < 2; ++qs) {
            o_[qs][d] = __builtin_amdgcn_mfma_f32_16x16x32_bf16(av0, pa[qs][0], o_[qs][d], 0, 0, 0);
            o_[qs][d] = __builtin_amdgcn_mfma_f32_16x16x32_bf16(av1, pa[qs][1], o_[qs][d], 0, 0, 0);
        }
    }
    __builtin_amdgcn_s_setprio(0);
}

__global__ __launch_bounds__(256, 2)
void attn_kernel(const __hip_bfloat16* __restrict__ Q,
                 const __hip_bfloat16* __restrict__ K,
                 const __hip_bfloat16* __restrict__ V,
                 __hip_bfloat16* __restrict__ O)
{
    __shared__ alignas(16) short Vlds[4*VPL];
    const int t = threadIdx.x, lane = t & 63, wave = t >> 6;
    const int g = lane >> 4, c = lane & 15;
    const int blk = blockIdx.x;
    const int qb = blk & 15;
    const int h  = (blk >> 4) & (Hn - 1);
    const int b  = blk >> 8;
    const size_t base = (size_t)b * Tn * Dn + (size_t)h * DHn;
    const int q0 = qb * 128 + wave * 32;

    short8 bq[2][2];
#pragma unroll
    for (int qs = 0; qs < 2; ++qs) {
        const __hip_bfloat16* qp = Q + base + (size_t)(q0 + qs*16 + c) * Dn + g*8;
        bq[qs][0] = *(const short8*)qp;
        bq[qs][1] = *(const short8*)(qp + 32);
    }

    f32x4 o_[2][4];
#pragma unroll
    for (int qs = 0; qs < 2; ++qs)
#pragma unroll
        for (int d = 0; d < 4; ++d) o_[qs][d] = fzero4();
    float m_[2] = {-3e38f, -3e38f};
    float l_[2] = {0.f, 0.f};

    const int vrow = t >> 3;
    const int vc   = (t >> 1) & 3;
    const int vh   = t & 1;
    const int vdst0 = vc*VPL + (vrow>>2)*80 + (vrow&3)*16 + vh*8;
    const uint32_t vbase = (uint32_t)(uintptr_t)(void*)Vlds;
    const uint32_t atr = vbase + (uint32_t)(g*160 + c*8);

    short8 akA[4][2], akB[4][2], vrA[2], vrB[2];
    // preload tile 0
    {
        const __hip_bfloat16* kp = K + base + (size_t)c * Dn + g*8;
#pragma unroll
        for (int sub = 0; sub < 4; ++sub)
#pragma unroll
            for (int ks = 0; ks < 2; ++ks)
                akA[sub][ks] = *(const short8*)(kp + (size_t)sub*16*Dn + ks*32);
        const __hip_bfloat16* vp = V + base + (size_t)vrow * Dn + vc*16 + vh*8;
        vrA[0] = *(const short8*)vp;
        vrA[1] = *(const short8*)(vp + (size_t)32*Dn);
    }

    for (int kv0 = 0; kv0 < Tn; kv0 += 128) {
        attn_tile(akA, vrA, akB, vrB, kv0 + 64, bq, o_, m_, l_,
                  K, V, base, c, g, vrow, vc, vh, vdst0, atr, Vlds);
        const int kvn = (kv0 + 128 < Tn) ? kv0 + 128 : 0;   // last prefetch unused
        attn_tile(akB, vrB, akA, vrA, kvn, bq, o_, m_, l_,
                  K, V, base, c, g, vrow, vc, vh, vdst0, atr, Vlds);
    }

#pragma unroll
    for (int qs = 0; qs < 2; ++qs) {
        const float inv = 1.f / l_[qs];
        __hip_bfloat16* op = O + base + (size_t)(q0 + qs*16 + c) * Dn + g*4;
#pragma unroll
        for (int d = 0; d < 4; ++d) {
            union { __hip_bfloat16 hb[4]; ushort4 u4; } w;
#pragma unroll
            for (int i = 0; i < 4; ++i) w.hb[i] = __float2bfloat16(o_[qs][d][i] * inv);
            *(ushort4*)(op + d*16) = w.u4;
        }
    }
}

extern "C" void kernel_launch(void* const* d_in, const int* in_sizes, int n_in,
                              void* d_out, int out_size, void* d_ws, size_t ws_size,
                              hipStream_t stream)
{
    (void)in_sizes; (void)n_in; (void)out_size; (void)ws_size;
    const float* q    = (const float*)d_in[0];
    const float* k    = (const float*)d_in[1];
    const float* v    = (const float*)d_in[2];
    const float* wq_w = (const float*)d_in[3];
    const float* wq_b = (const float*)d_in[4];
    const float* wk_w = (const float*)d_in[5];
    const float* wk_b = (const float*)d_in[6];
    const float* wv_w = (const float*)d_in[7];
    const float* wv_b = (const float*)d_in[8];
    const float* wo_w = (const float*)d_in[9];
    const float* wo_b = (const float*)d_in[10];

    char* ws = (char*)d_ws;
    const size_t S1 = (size_t)Mn * Dn * 2;
    const size_t W  = (size_t)Dn * Dn * 2;
    __hip_bfloat16* qb  = (__hip_bfloat16*)(ws);
    __hip_bfloat16* kb  = (__hip_bfloat16*)(ws + S1);
    __hip_bfloat16* vb  = (__hip_bfloat16*)(ws + 2*S1);
    __hip_bfloat16* wqb = (__hip_bfloat16*)(ws + 3*S1);
    __hip_bfloat16* wkb = (__hip_bfloat16*)(ws + 3*S1 + W);
    __hip_bfloat16* wvb = (__hip_bfloat16*)(ws + 3*S1 + 2*W);
    __hip_bfloat16* wob = (__hip_bfloat16*)(ws + 3*S1 + 3*W);
    __hip_bfloat16* Qp  = (__hip_bfloat16*)(ws + 3*S1 + 4*W);
    __hip_bfloat16* Kp  = (__hip_bfloat16*)(ws + 4*S1 + 4*W);
    __hip_bfloat16* Vp  = (__hip_bfloat16*)(ws + 5*S1 + 4*W);
    __hip_bfloat16* Ap  = (__hip_bfloat16*)(ws + 6*S1 + 4*W);

    const int nQKV = Mn * Dn;
    const int nW   = Dn * Dn;
    cvt3_kernel<<<dim3(nQKV/2048, 3), 256, 0, stream>>>(q, k, v, qb, kb, vb, nQKV);
    cvt4_kernel<<<dim3(nW/2048, 4), 256, 0, stream>>>(wq_w, wk_w, wv_w, wo_w,
                                                      wqb, wkb, wvb, wob, nW);

    dim3 g(Mn/128, Dn/128);
    gemm_bt_kernel<0><<<g, 256, 0, stream>>>(qb, wqb, wq_b, Qp, Mn, Dn, Dn);
    gemm_bt_kernel<0><<<g, 256, 0, stream>>>(kb, wkb, wk_b, Kp, Mn, Dn, Dn);
    gemm_bt_kernel<0><<<g, 256, 0, stream>>>(vb, wvb, wv_b, Vp, Mn, Dn, Dn);

    attn_kernel<<<Bn*Hn*(Tn/128), 256, 0, stream>>>(Qp, Kp, Vp, Ap);

    gemm_bt_kernel<1><<<g, 256, 0, stream>>>(Ap, wob, wo_b, (float*)d_out, Mn, Dn, Dn);
}